// Round 16
// baseline (70.651 us; speedup 1.0000x reference)
//
#include <hip/hip_runtime.h>
#include <cstdint>
#include <cstddef>

typedef unsigned short us;
using short8 = __attribute__((ext_vector_type(8))) short;  // 8 bf16
using f32x4  = __attribute__((ext_vector_type(4))) float;

union U8 { us u[8]; short8 v; };
union PU { int w[4]; short8 v; };

#define MFMA16(a,b,c) __builtin_amdgcn_mfma_f32_16x16x32_bf16((a),(b),(c),0,0,0)

static __device__ __forceinline__ us f2bf(float f){
  union { float f; unsigned u; } cv; cv.f = f;
  unsigned u = cv.u;
  return (us)((u + 0x7fffu + ((u >> 16) & 1u)) >> 16);
}

typedef const __attribute__((address_space(1))) void* gp_t;
typedef __attribute__((address_space(3))) void* lp_t;
#define GL16(g,l) __builtin_amdgcn_global_load_lds((gp_t)(g),(lp_t)(l),16,0,0)

// ---------------------------------------------------------------------------
// prep (FUSED, r15-proven): per-batch compacted K/V (dst row = b*1024+rank),
// k/v blocks recompute their own batch's mask scan in LDS.
// ---------------------------------------------------------------------------
__global__ __launch_bounds__(256) void prep(
    const float* __restrict__ xq, const float* __restrict__ xk, const float* __restrict__ xv,
    const float* __restrict__ Wq, const float* __restrict__ Wk,
    const float* __restrict__ Wv, const float* __restrict__ Wo,
    const int* __restrict__ mask,
    us* __restrict__ xbq, us* __restrict__ xbk, us* __restrict__ xbv,
    us* __restrict__ wb, f32x4* __restrict__ zreg, int* __restrict__ nbd)
{
  const int bid = blockIdx.x, tid = threadIdx.x;
  __shared__ int wsum[4];
  __shared__ short srank[1024];

  if (bid < 4){                              // batch totals only
    const int b = bid, lane = tid & 63, w = tid >> 6;
    int cnt = 0;
#pragma unroll
    for (int j = 0; j < 4; ++j) cnt += mask[b * 1024 + tid * 4 + j] ? 0 : 1;
#pragma unroll
    for (int off = 1; off < 64; off <<= 1) cnt += __shfl_xor(cnt, off, 64);
    if (lane == 0) wsum[w] = cnt;
    __syncthreads();
    if (tid == 0) nbd[b] = wsum[0] + wsum[1] + wsum[2] + wsum[3];
    return;
  }
  const float* src; us* dst;
  if (bid < 1156){                           // W chunks
    unsigned wi = (bid - 4) * 256u + tid;
    unsigned z  = wi / 73728u;
    unsigned rr = wi - z * 73728u;
    const float* W = (z == 0) ? Wq : (z == 1) ? Wk : (z == 2) ? Wv : Wo;
    src = W  + (size_t)rr * 8u;
    dst = wb + (size_t)z * 589824u + rr * 8u;
  } else if (bid < 2692){                    // q chunks
    unsigned id = (bid - 1156) * 256u + tid;
    unsigned row = id / 96u, cc = id - row * 96u;
    unsigned bsel = row >> 10, n = row & 1023u;
    src = xq  + (size_t)(n * 4u + bsel) * 768u + cc * 8u;
    dst = xbq + (size_t)row * 768u + cc * 8u;
  } else if (bid < 4228){                    // zero vtc (6.29 MB)
    zreg[(size_t)(bid - 2692) * 256 + tid] = f32x4{};
    return;
  } else {                                   // k/v with redundant own-batch scan
    unsigned id = (bid - 4228) * 256u + tid;
    unsigned z  = id / 393216u;
    unsigned rr = id - z * 393216u;
    unsigned row = rr / 96u, cc = rr - row * 96u;
    unsigned bsel = row >> 10, n = row & 1023u;

    const int lane = tid & 63, w = tid >> 6;
    int m[4], cnt = 0;
#pragma unroll
    for (int j = 0; j < 4; ++j){
      m[j] = mask[bsel * 1024 + tid * 4 + j] ? 0 : 1;
      cnt += m[j];
    }
    int sc = cnt;
#pragma unroll
    for (int off = 1; off < 64; off <<= 1){
      int t = __shfl_up(sc, off, 64);
      if (lane >= off) sc += t;
    }
    if (lane == 63) wsum[w] = sc;
    __syncthreads();
    int woff = 0;
#pragma unroll
    for (int i = 0; i < 4; ++i) if (i < w) woff += wsum[i];
    int rr2 = woff + sc - cnt;
#pragma unroll
    for (int j = 0; j < 4; ++j){
      srank[tid * 4 + j] = (short)(m[j] ? rr2 : -1);
      rr2 += m[j];
    }
    __syncthreads();
    int rk = srank[n];
    if (rk < 0) return;
    src = ((z == 0) ? xk : xv) + (size_t)(n * 4u + bsel) * 768u + cc * 8u;
    dst = ((z == 0) ? xbk : xbv) + (size_t)(bsel * 1024u + rk) * 768u + cc * 8u;
  }
  f32x4 a = *(const f32x4*)src;
  f32x4 b = *(const f32x4*)(src + 4);
  U8 o;
#pragma unroll
  for (int j = 0; j < 4; ++j){ o.u[j] = f2bf(a[j]); o.u[4 + j] = f2bf(b[j]); }
  *(short8*)dst = o.v;
}

// ---------------------------------------------------------------------------
// QKV projection v10: 64x128 tile, 256 threads / 4 waves (wave grid 2x2,
// 32x64 per wave), 48 KB LDS -> 3 blocks/CU; 768 live blocks = exact 3/CU
// balance (fixes the 1.5-blocks/CU imbalance of the 128-row version).
// Depth-2 vmcnt(6) pipeline, T2 swizzle, XCD remaps.
// ---------------------------------------------------------------------------
__global__ __launch_bounds__(256, 3) void qkv_gemm10(
    const us* __restrict__ xbq, const us* __restrict__ xbk, const us* __restrict__ xbv,
    const us* __restrict__ wb,
    const float* __restrict__ bq, const float* __restrict__ bk, const float* __restrict__ bv,
    const float* __restrict__ zeta, const int* __restrict__ nbd,
    us* __restrict__ qh, us* __restrict__ kc, us* __restrict__ vtc)
{
  const int z = blockIdx.z;
  int mt, nt;
  if (z == 0){
    const int flat = blockIdx.x + blockIdx.y * 64;  // [0,384)
    const int xcd = flat & 7, c = flat >> 3;        // c in [0,48)
    mt = xcd * 8 + (c & 7);                         // 64-row tiles, [0,64)
    nt = c >> 3;                                    // [0,6)
  } else {
    const int mtv0 = (nbd[0] + 63) >> 6, mtv1 = (nbd[1] + 63) >> 6;
    const int mtv2 = (nbd[2] + 63) >> 6, mtv3 = (nbd[3] + 63) >> 6;
    const int nlive = 6 * (mtv0 + mtv1 + mtv2 + mtv3);
    const int c = blockIdx.x + blockIdx.y * 64;     // [0,384)
    const int xcd = c & 7, j = c >> 3;
    const int qd = nlive >> 3, rm = nlive & 7;
    const int cnt = qd + (xcd < rm ? 1 : 0);
    if (j >= cnt) return;
    const int start = xcd * qd + (xcd < rm ? xcd : rm);
    const int wk = start + j;
    int mti = wk / 6;
    nt = wk - mti * 6;
    int bsel2 = 0, t = mti;
    if (t >= mtv0){ t -= mtv0; bsel2 = 1;
      if (t >= mtv1){ t -= mtv1; bsel2 = 2;
        if (t >= mtv2){ t -= mtv2; bsel2 = 3; } } }
    mt = bsel2 * 16 + t;                            // per-batch 16-tile segments
  }
  const us* A  = (z == 0) ? xbq : (z == 1) ? xbk : xbv;
  const us* Bw = wb + (size_t)z * 589824;
  const float* bias = (z == 0) ? bq : (z == 1) ? bk : bv;

  __shared__ __align__(16) us As[2][64 * 64];
  __shared__ __align__(16) us Bs[2][128 * 64];

  const int tid = threadIdx.x, lane = tid & 63, w = tid >> 6;
  const int wr = (w >> 1) * 32, wc = (w & 1) * 64;

  f32x4 acc[2][4] = {};

  auto STAGE = [&](int kt, int buf){
    // A: 64x64 tile = 512 chunks (2/thread)
#pragma unroll
    for (int p = 0; p < 2; ++p){
      int c = p * 256 + tid;
      int row = c >> 3;
      int colb = ((c & 7) ^ (row & 7)) * 8;
      GL16(A + (size_t)(mt * 64 + row) * 768 + kt * 64 + colb,
           As[buf] + (p * 256 + w * 64) * 8);
    }
    // B: 128x64 tile = 1024 chunks (4/thread)
#pragma unroll
    for (int p = 0; p < 4; ++p){
      int c = p * 256 + tid;
      int row = c >> 3;
      int colb = ((c & 7) ^ (row & 7)) * 8;
      GL16(Bw + (size_t)(nt * 128 + row) * 768 + kt * 64 + colb,
           Bs[buf] + (p * 256 + w * 64) * 8);
    }
  };

  STAGE(0, 0);
  STAGE(1, 1);
  for (int kt = 0; kt < 12; ++kt){
    const int cur = kt & 1;
    if (kt < 11) asm volatile("s_waitcnt vmcnt(6)" ::: "memory");
    else         asm volatile("s_waitcnt vmcnt(0)" ::: "memory");
    __builtin_amdgcn_s_barrier();

#pragma unroll
    for (int ks = 0; ks < 2; ++ks){
      short8 af[2], bf4[4];
#pragma unroll
      for (int mf = 0; mf < 2; ++mf){
        int row = wr + mf * 16 + (lane & 15);
        int byte = (row * 128 + ks * 64 + (lane >> 4) * 16) ^ ((row & 7) << 4);
        af[mf] = *(const short8*)((const char*)As[cur] + byte);
      }
#pragma unroll
      for (int nf = 0; nf < 4; ++nf){
        int row = wc + nf * 16 + (lane & 15);
        int byte = (row * 128 + ks * 64 + (lane >> 4) * 16) ^ ((row & 7) << 4);
        bf4[nf] = *(const short8*)((const char*)Bs[cur] + byte);
      }
#pragma unroll
      for (int mf = 0; mf < 2; ++mf)
#pragma unroll
        for (int nf = 0; nf < 4; ++nf)
          acc[mf][nf] = MFMA16(af[mf], bf4[nf], acc[mf][nf]);
    }

    asm volatile("s_waitcnt lgkmcnt(0)" ::: "memory");
    __builtin_amdgcn_s_barrier();
    if (kt < 10) STAGE(kt + 2, cur);
  }

  float bzv[4], zzv[4]; int colv[4];
#pragma unroll
  for (int nf = 0; nf < 4; ++nf){
    colv[nf] = nt * 128 + wc + nf * 16 + (lane & 15);
    bzv[nf] = bias[colv[nf]];
    zzv[nf] = zeta[colv[nf]];
  }

  if (z == 0){
#pragma unroll
    for (int mf = 0; mf < 2; ++mf)
#pragma unroll
      for (int r = 0; r < 4; ++r){
        int row = mt * 64 + wr + mf * 16 + (lane >> 4) * 4 + r;
#pragma unroll
        for (int nf = 0; nf < 4; ++nf)
          qh[(size_t)row * 768 + colv[nf]] = f2bf((acc[mf][nf][r] + bzv[nf]) * zzv[nf]);
      }
  } else {
    const int bsel = mt >> 4;
    const int base_b = bsel << 10;
    const int nb = nbd[bsel];
#pragma unroll
    for (int mf = 0; mf < 2; ++mf)
#pragma unroll
      for (int r = 0; r < 4; ++r){
        int grow = mt * 64 + wr + mf * 16 + (lane >> 4) * 4 + r;
        int row_local = grow - base_b;
        if (row_local >= nb) continue;       // pad row (kc garbage OK; vtc stays 0)
        if (z == 1){
#pragma unroll
          for (int nf = 0; nf < 4; ++nf)
            kc[(size_t)grow * 768 + colv[nf]] =
                f2bf((acc[mf][nf][r] + bzv[nf]) * zzv[nf]);
        } else {
#pragma unroll
          for (int nf = 0; nf < 4; ++nf){
            int hh = colv[nf] >> 6, dd = colv[nf] & 63;
            vtc[((size_t)(bsel * 12 + hh) * 64 + dd) * 1024 + row_local] =
                f2bf((acc[mf][nf][r] + bzv[nf]) * zzv[nf]);
          }
        }
      }
  }
}

// ---------------------------------------------------------------------------
// Flash attention (r11-proven attn_fwd7): 4 waves, K/V double-buffered in
// LDS, swapped-QK^T in-register-P, T5 setprio.  kc base = b*1024.
// ---------------------------------------------------------------------------
__global__ __launch_bounds__(256) void attn_fwd7(
    const us* __restrict__ qh, const us* __restrict__ kc,
    const us* __restrict__ vtc, const int* __restrict__ nbd,
    us* __restrict__ ao)
{
  const int flat = blockIdx.x + 16 * blockIdx.y + 192 * blockIdx.z;
  const int xcd = flat & 7, c = flat >> 3;
  const int pair = xcd * 6 + (c >> 4);
  const int qt = c & 15, h = pair % 12, b = pair / 12;
  const int tid = threadIdx.x, lane = tid & 63, w = tid >> 6;

  const int nbv = nbd[b];
  const int base_b = b << 10;
  const int nt = (nbv + 63) >> 6;

  __shared__ __align__(16) us Ks[2][64 * 64];
  __shared__ __align__(16) us Vs[2][64 * 64];

  short8 qf[2];
#pragma unroll
  for (int ks = 0; ks < 2; ++ks)
    qf[ks] = *(const short8*)(qh +
              (size_t)(b * 1024 + qt * 64 + w * 16 + (lane & 15)) * 768 +
              h * 64 + ks * 32 + (lane >> 4) * 8);

  short8 kr[2], vr[2];
  auto KVLOAD = [&](int kt){
#pragma unroll
    for (int p = 0; p < 2; ++p){
      int cc = p * 256 + tid, row = cc >> 3, db = (cc & 7) * 8;
      kr[p] = *(const short8*)(kc + (size_t)(base_b + kt * 64 + row) * 768 + h * 64 + db);
      vr[p] = *(const short8*)(vtc + ((size_t)((b * 12 + h) * 64 + row)) * 1024 + kt * 64 + db);
    }
  };
  auto KVWRITE = [&](int buf){
#pragma unroll
    for (int p = 0; p < 2; ++p){
      int cc = p * 256 + tid, row = cc >> 3, db = (cc & 7) * 8;
      int byte = (row * 128 + db * 2) ^ ((row & 7) << 4);
      *(short8*)((char*)Ks[buf] + byte) = kr[p];
      *(short8*)((char*)Vs[buf] + byte) = vr[p];
    }
  };
  KVLOAD(0); KVWRITE(0);
  __syncthreads();

  const int bpbase = (((lane & 16) << 1) | (lane & 15)) << 2;
  const bool hi5 = (lane & 32) != 0;

  float lsum = 0.f;
  f32x4 o[4] = {};
  int cur = 0;
  for (int kt = 0; kt < nt; ++kt){
    if (kt + 1 < nt) KVLOAD(kt + 1);

    f32x4 s[4] = {};
    __builtin_amdgcn_s_setprio(1);
#pragma unroll
    for (int ks = 0; ks < 2; ++ks)
#pragma unroll
      for (int f = 0; f < 4; ++f){
        int row = f * 16 + (lane & 15);
        short8 kf = *(const short8*)((const char*)Ks[cur] +
                    ((row * 128 + ks * 64 + (lane >> 4) * 16) ^ ((row & 7) << 4)));
        s[f] = MFMA16(kf, qf[ks], s[f]);
      }
    __builtin_amdgcn_s_setprio(0);

    float p_[4][4];
#pragma unroll
    for (int f = 0; f < 4; ++f)
#pragma unroll
      for (int r = 0; r < 4; ++r)
        p_[f][r] = __expf(s[f][r] * 0.125f);
    if (kt == nt - 1){
      int kb = kt * 64 + ((lane >> 4) << 2);
#pragma unroll
      for (int f = 0; f < 4; ++f)
#pragma unroll
        for (int r = 0; r < 4; ++r)
          p_[f][r] = (kb + f * 16 + r < nbv) ? p_[f][r] : 0.f;
    }
#pragma unroll
    for (int f = 0; f < 4; ++f)
      lsum += (p_[f][0] + p_[f][1]) + (p_[f][2] + p_[f][3]);

    unsigned pk[4][2];
#pragma unroll
    for (int f = 0; f < 4; ++f){
      pk[f][0] = (unsigned)f2bf(p_[f][0]) | ((unsigned)f2bf(p_[f][1]) << 16);
      pk[f][1] = (unsigned)f2bf(p_[f][2]) | ((unsigned)f2bf(p_[f][3]) << 16);
    }

    PU pa0, pa1;
#pragma unroll
    for (int j = 0; j < 4; ++j){
      int addr = bpbase + ((j & 2) << 5);
      int wsel = j & 1;
      int t0 = __builtin_amdgcn_ds_bpermute(addr, (int)pk[0][wsel]);
      int t1 = __builtin_amdgcn_ds_bpermute(addr, (int)pk[1][wsel]);
      int t2 = __builtin_amdgcn_ds_bpermute(addr, (int)pk[2][wsel]);
      int t3 = __builtin_amdgcn_ds_bpermute(addr, (int)pk[3][wsel]);
      pa0.w[j] = hi5 ? t1 : t0;
      pa1.w[j] = hi5 ? t3 : t2;
    }

    __builtin_amdgcn_s_setprio(1);
#pragma unroll
    for (int df = 0; df < 4; ++df){
      int vrow = df * 16 + (lane & 15);
      short8 vb0 = *(const short8*)((const char*)Vs[cur] +
                   ((vrow * 128 + 0  + (lane >> 4) * 16) ^ ((vrow & 7) << 4)));
      short8 vb1 = *(const short8*)((const char*)Vs[cur] +
                   ((vrow * 128 + 64 + (lane >> 4) * 16) ^ ((vrow & 7) << 4)));
      o[df] = MFMA16(pa0.v, vb0, o[df]);
      o[df] = MFMA16(pa1.v, vb1, o[df]);
    }
    __builtin_amdgcn_s_setprio(0);

    if (kt + 1 < nt) KVWRITE(cur ^ 1);
    __syncthreads();
    cur ^= 1;
  }

  float l = lsum;
  l += __shfl_xor(l, 16, 64);
  l += __shfl_xor(l, 32, 64);
  float linv[4];
#pragma unroll
  for (int r = 0; r < 4; ++r)
    linv[r] = __builtin_amdgcn_rcpf(__shfl(l, (lane >> 4) * 4 + r, 64));

#pragma unroll
  for (int df = 0; df < 4; ++df)
#pragma unroll
    for (int r = 0; r < 4; ++r){
      int qrow = qt * 64 + w * 16 + (lane >> 4) * 4 + r;
      int dcol = df * 16 + (lane & 15);
      ao[(size_t)(b * 1024 + qrow) * 768 + h * 64 + dcol] = f2bf(o[df][r] * linv[r]);
    }
}

// ---------------------------------------------------------------------------
// Output projection: 512-thread / 8-wave template (r14-proven).
// ---------------------------------------------------------------------------
__global__ __launch_bounds__(512, 1) void out_gemm8(
    const us* __restrict__ ain, const us* __restrict__ wo,
    const float* __restrict__ bo, float* __restrict__ dout)
{
  __shared__ __align__(16) us As[2][128 * 64];
  __shared__ __align__(16) us Bs[2][128 * 64];

  const int tid = threadIdx.x, lane = tid & 63, w = tid >> 6;
  const int wr = (w >> 1) * 32, wc = (w & 1) * 64;
  const int flat = blockIdx.x + blockIdx.y * 32;
  const int xcd = flat & 7, c = flat >> 3;
  const int mt = xcd * 4 + (c & 3);
  const int nt = c >> 2;

  f32x4 acc[2][4] = {};

  auto STAGE = [&](int kt, int buf){
#pragma unroll
    for (int p = 0; p < 2; ++p){
      int chunk = p * 512 + tid;
      int row = chunk >> 3;
      int colb = ((chunk & 7) ^ (row & 7)) * 8;
      GL16(ain + (size_t)(mt * 128 + row) * 768 + kt * 64 + colb,
           As[buf] + (p * 512 + w * 64) * 8);
      GL16(wo  + (size_t)(nt * 128 + row) * 768 + kt * 64 + colb,
           Bs[buf] + (p * 512 + w * 64) * 8);
    }
  };

  STAGE(0, 0);
  STAGE(1, 1);
  for (int kt = 0; kt < 12; ++kt){
    const int cur = kt & 1;
    if (kt < 11) asm volatile("s_waitcnt vmcnt(4)" ::: "memory");
    else         asm volatile("s_waitcnt vmcnt(0)" ::: "memory");
    __builtin_amdgcn_s_barrier();

#pragma unroll
    for (int ks = 0; ks < 2; ++ks){
      short8 af[2], bf4[4];
#pragma unroll
      for (int mf = 0; mf < 2; ++mf){
        int row = wr + mf * 16 + (lane & 15);
        int byte = (row * 128 + ks * 64 + (lane >> 4) * 16) ^ ((row & 7) << 4);
        af[mf] = *(const short8*)((const char*)As[cur] + byte);
      }
#pragma unroll
      for (int nf = 0; nf < 4; ++nf){
        int row = wc + nf * 16 + (lane & 15);
        int byte = (row * 128 + ks * 64 + (lane >> 4) * 16) ^ ((row & 7) << 4);
        bf4[nf] = *(const short8*)((const char*)Bs[cur] + byte);
      }
#pragma unroll
      for (int mf = 0; mf < 2; ++mf)
#pragma unroll
        for (int nf = 0; nf < 4; ++nf)
          acc[mf][nf] = MFMA16(af[mf], bf4[nf], acc[mf][nf]);
    }

    asm volatile("s_waitcnt lgkmcnt(0)" ::: "memory");
    __builtin_amdgcn_s_barrier();
    if (kt < 10) STAGE(kt + 2, cur);
  }

#pragma unroll
  for (int nf = 0; nf < 4; ++nf){
    int col = nt * 128 + wc + nf * 16 + (lane & 15);
    float bz = bo[col];
#pragma unroll
    for (int mf = 0; mf < 2; ++mf)
#pragma unroll
      for (int r = 0; r < 4; ++r){
        int row = mt * 128 + wr + mf * 16 + (lane >> 4) * 4 + r;
        int n = row & 1023, bsel = row >> 10;
        dout[(size_t)(n * 4 + bsel) * 768 + col] = acc[mf][nf][r] + bz;
      }
  }
}

extern "C" void kernel_launch(void* const* d_in, const int* in_sizes, int n_in,
                              void* d_out, int out_size, void* d_ws, size_t ws_size,
                              hipStream_t stream)
{
  const float* q    = (const float*)d_in[0];
  const float* k    = (const float*)d_in[1];
  const float* v    = (const float*)d_in[2];
  const int*   mask = (const int*)d_in[3];
  const float* Wq   = (const float*)d_in[4];
  const float* bq   = (const float*)d_in[5];
  const float* Wk   = (const float*)d_in[6];
  const float* bk   = (const float*)d_in[7];
  const float* Wv   = (const float*)d_in[8];
  const float* bv   = (const float*)d_in[9];
  const float* Wo   = (const float*)d_in[10];
  const float* bo   = (const float*)d_in[11];
  const float* zeta = (const float*)d_in[12];

  // bf16 xq + per-batch-compacted xk parked inside d_out
  us* xbq = (us*)d_out;
  us* xbk = xbq + 3145728;
  // workspace layout
  us* xbv = (us*)d_ws;          // per-batch compacted rows [b*1024+rank][768]
  us* wb  = xbv + 3145728;      // 4 x 768 x 768 bf16 weights
  us* qh  = wb  + 2359296;
  us* kc  = qh  + 3145728;      // compacted K [b*1024+rank][768] (pad garbage OK)
  us* vtc = kc  + 3145728;      // compacted V^T [b][h][d][rank] (pad zeroed)
  int* nbd = (int*)(vtc + 3145728);
  us* ao = xbv;                 // reuse: xbv dead after qkv_gemm10

  prep<<<7300, 256, 0, stream>>>(q, k, v, Wq, Wk, Wv, Wo, mask,
                                 xbq, xbk, xbv, wb, (f32x4*)vtc, nbd);
  qkv_gemm10<<<dim3(64, 6, 3), 256, 0, stream>>>(xbq, xbk, xbv, wb, bq, bk, bv,
                                                 zeta, nbd, qh, kc, vtc);
  attn_fwd7<<<dim3(16, 12, 4), 256, 0, stream>>>(qh, kc, vtc, nbd, ao);
  out_gemm8<<<dim3(32, 6, 1), 512, 0, stream>>>(ao, wb + 3 * 589824, bo, (float*)d_out);
}

// Round 17
// 66.711 us; speedup vs baseline: 1.0591x; 1.0591x over previous
//
#include <hip/hip_runtime.h>
#include <cstdint>
#include <cstddef>

typedef unsigned short us;
using short8 = __attribute__((ext_vector_type(8))) short;  // 8 bf16
using f32x4  = __attribute__((ext_vector_type(4))) float;

union U8 { us u[8]; short8 v; };
union PU { int w[4]; short8 v; };

#define MFMA16(a,b,c) __builtin_amdgcn_mfma_f32_16x16x32_bf16((a),(b),(c),0,0,0)

static __device__ __forceinline__ us f2bf(float f){
  union { float f; unsigned u; } cv; cv.f = f;
  unsigned u = cv.u;
  return (us)((u + 0x7fffu + ((u >> 16) & 1u)) >> 16);
}

typedef const __attribute__((address_space(1))) void* gp_t;
typedef __attribute__((address_space(3))) void* lp_t;
#define GL16(g,l) __builtin_amdgcn_global_load_lds((gp_t)(g),(lp_t)(l),16,0,0)

// ---------------------------------------------------------------------------
// prep (FUSED, r15-proven): per-batch compacted K/V (dst row = b*1024+rank),
// k/v blocks recompute their own batch's mask scan in LDS.
// ---------------------------------------------------------------------------
__global__ __launch_bounds__(256) void prep(
    const float* __restrict__ xq, const float* __restrict__ xk, const float* __restrict__ xv,
    const float* __restrict__ Wq, const float* __restrict__ Wk,
    const float* __restrict__ Wv, const float* __restrict__ Wo,
    const int* __restrict__ mask,
    us* __restrict__ xbq, us* __restrict__ xbk, us* __restrict__ xbv,
    us* __restrict__ wb, f32x4* __restrict__ zreg, int* __restrict__ nbd)
{
  const int bid = blockIdx.x, tid = threadIdx.x;
  __shared__ int wsum[4];
  __shared__ short srank[1024];

  if (bid < 4){                              // batch totals only
    const int b = bid, lane = tid & 63, w = tid >> 6;
    int cnt = 0;
#pragma unroll
    for (int j = 0; j < 4; ++j) cnt += mask[b * 1024 + tid * 4 + j] ? 0 : 1;
#pragma unroll
    for (int off = 1; off < 64; off <<= 1) cnt += __shfl_xor(cnt, off, 64);
    if (lane == 0) wsum[w] = cnt;
    __syncthreads();
    if (tid == 0) nbd[b] = wsum[0] + wsum[1] + wsum[2] + wsum[3];
    return;
  }
  const float* src; us* dst;
  if (bid < 1156){                           // W chunks
    unsigned wi = (bid - 4) * 256u + tid;
    unsigned z  = wi / 73728u;
    unsigned rr = wi - z * 73728u;
    const float* W = (z == 0) ? Wq : (z == 1) ? Wk : (z == 2) ? Wv : Wo;
    src = W  + (size_t)rr * 8u;
    dst = wb + (size_t)z * 589824u + rr * 8u;
  } else if (bid < 2692){                    // q chunks
    unsigned id = (bid - 1156) * 256u + tid;
    unsigned row = id / 96u, cc = id - row * 96u;
    unsigned bsel = row >> 10, n = row & 1023u;
    src = xq  + (size_t)(n * 4u + bsel) * 768u + cc * 8u;
    dst = xbq + (size_t)row * 768u + cc * 8u;
  } else if (bid < 4228){                    // zero vtc (6.29 MB)
    zreg[(size_t)(bid - 2692) * 256 + tid] = f32x4{};
    return;
  } else {                                   // k/v with redundant own-batch scan
    unsigned id = (bid - 4228) * 256u + tid;
    unsigned z  = id / 393216u;
    unsigned rr = id - z * 393216u;
    unsigned row = rr / 96u, cc = rr - row * 96u;
    unsigned bsel = row >> 10, n = row & 1023u;

    const int lane = tid & 63, w = tid >> 6;
    int m[4], cnt = 0;
#pragma unroll
    for (int j = 0; j < 4; ++j){
      m[j] = mask[bsel * 1024 + tid * 4 + j] ? 0 : 1;
      cnt += m[j];
    }
    int sc = cnt;
#pragma unroll
    for (int off = 1; off < 64; off <<= 1){
      int t = __shfl_up(sc, off, 64);
      if (lane >= off) sc += t;
    }
    if (lane == 63) wsum[w] = sc;
    __syncthreads();
    int woff = 0;
#pragma unroll
    for (int i = 0; i < 4; ++i) if (i < w) woff += wsum[i];
    int rr2 = woff + sc - cnt;
#pragma unroll
    for (int j = 0; j < 4; ++j){
      srank[tid * 4 + j] = (short)(m[j] ? rr2 : -1);
      rr2 += m[j];
    }
    __syncthreads();
    int rk = srank[n];
    if (rk < 0) return;
    src = ((z == 0) ? xk : xv) + (size_t)(n * 4u + bsel) * 768u + cc * 8u;
    dst = ((z == 0) ? xbk : xbv) + (size_t)(bsel * 1024u + rk) * 768u + cc * 8u;
  }
  f32x4 a = *(const f32x4*)src;
  f32x4 b = *(const f32x4*)(src + 4);
  U8 o;
#pragma unroll
  for (int j = 0; j < 4; ++j){ o.u[j] = f2bf(a[j]); o.u[4 + j] = f2bf(b[j]); }
  *(short8*)dst = o.v;
}

// ---------------------------------------------------------------------------
// QKV projection: 512 threads / 8 waves, 128x128 tile, vmcnt(4) depth-2
// pipeline, T2 swizzle (r11/r15-proven).  z=1/2 live tiles are per-batch
// segments: mt = b*8 + local_tile, local_tile < ceil(nb_b/128).
// ---------------------------------------------------------------------------
__global__ __launch_bounds__(512, 1) void qkv_gemm9(
    const us* __restrict__ xbq, const us* __restrict__ xbk, const us* __restrict__ xbv,
    const us* __restrict__ wb,
    const float* __restrict__ bq, const float* __restrict__ bk, const float* __restrict__ bv,
    const float* __restrict__ zeta, const int* __restrict__ nbd,
    us* __restrict__ qh, us* __restrict__ kc, us* __restrict__ vtc)
{
  const int z = blockIdx.z;
  int mt, nt;
  if (z == 0){
    const int flat = blockIdx.x + blockIdx.y * 32;
    const int xcd = flat & 7, c = flat >> 3;
    mt = xcd * 4 + (c & 3);
    nt = c >> 2;
  } else {
    const int mtv0 = (nbd[0] + 127) >> 7, mtv1 = (nbd[1] + 127) >> 7;
    const int mtv2 = (nbd[2] + 127) >> 7, mtv3 = (nbd[3] + 127) >> 7;
    const int nlive = 6 * (mtv0 + mtv1 + mtv2 + mtv3);
    const int c = blockIdx.x + blockIdx.y * 32;     // 0..191
    const int xcd = c & 7, j = c >> 3;
    const int qd = nlive >> 3, rm = nlive & 7;
    const int cnt = qd + (xcd < rm ? 1 : 0);
    if (j >= cnt) return;
    const int start = xcd * qd + (xcd < rm ? xcd : rm);
    const int wk = start + j;
    int mti = wk / 6;
    nt = wk - mti * 6;
    int bsel2 = 0, t = mti;                         // map live index -> (b, local)
    if (t >= mtv0){ t -= mtv0; bsel2 = 1;
      if (t >= mtv1){ t -= mtv1; bsel2 = 2;
        if (t >= mtv2){ t -= mtv2; bsel2 = 3; } } }
    mt = bsel2 * 8 + t;
  }
  const us* A  = (z == 0) ? xbq : (z == 1) ? xbk : xbv;
  const us* Bw = wb + (size_t)z * 589824;
  const float* bias = (z == 0) ? bq : (z == 1) ? bk : bv;

  __shared__ __align__(16) us As[2][128 * 64];
  __shared__ __align__(16) us Bs[2][128 * 64];

  const int tid = threadIdx.x, lane = tid & 63, w = tid >> 6;
  const int wr = (w >> 1) * 32, wc = (w & 1) * 64;

  f32x4 acc[2][4] = {};

  auto STAGE = [&](int kt, int buf){
#pragma unroll
    for (int p = 0; p < 2; ++p){
      int chunk = p * 512 + tid;
      int row = chunk >> 3;
      int colb = ((chunk & 7) ^ (row & 7)) * 8;
      GL16(A  + (size_t)(mt * 128 + row) * 768 + kt * 64 + colb,
           As[buf] + (p * 512 + w * 64) * 8);
      GL16(Bw + (size_t)(nt * 128 + row) * 768 + kt * 64 + colb,
           Bs[buf] + (p * 512 + w * 64) * 8);
    }
  };

  STAGE(0, 0);
  STAGE(1, 1);
  for (int kt = 0; kt < 12; ++kt){
    const int cur = kt & 1;
    if (kt < 11) asm volatile("s_waitcnt vmcnt(4)" ::: "memory");
    else         asm volatile("s_waitcnt vmcnt(0)" ::: "memory");
    __builtin_amdgcn_s_barrier();

#pragma unroll
    for (int ks = 0; ks < 2; ++ks){
      short8 af[2], bf4[4];
#pragma unroll
      for (int mf = 0; mf < 2; ++mf){
        int row = wr + mf * 16 + (lane & 15);
        int byte = (row * 128 + ks * 64 + (lane >> 4) * 16) ^ ((row & 7) << 4);
        af[mf] = *(const short8*)((const char*)As[cur] + byte);
      }
#pragma unroll
      for (int nf = 0; nf < 4; ++nf){
        int row = wc + nf * 16 + (lane & 15);
        int byte = (row * 128 + ks * 64 + (lane >> 4) * 16) ^ ((row & 7) << 4);
        bf4[nf] = *(const short8*)((const char*)Bs[cur] + byte);
      }
#pragma unroll
      for (int mf = 0; mf < 2; ++mf)
#pragma unroll
        for (int nf = 0; nf < 4; ++nf)
          acc[mf][nf] = MFMA16(af[mf], bf4[nf], acc[mf][nf]);
    }

    asm volatile("s_waitcnt lgkmcnt(0)" ::: "memory");
    __builtin_amdgcn_s_barrier();
    if (kt < 10) STAGE(kt + 2, cur);
  }

  float bzv[4], zzv[4]; int colv[4];
#pragma unroll
  for (int nf = 0; nf < 4; ++nf){
    colv[nf] = nt * 128 + wc + nf * 16 + (lane & 15);
    bzv[nf] = bias[colv[nf]];
    zzv[nf] = zeta[colv[nf]];
  }

  if (z == 0){
#pragma unroll
    for (int mf = 0; mf < 2; ++mf)
#pragma unroll
      for (int r = 0; r < 4; ++r){
        int row = mt * 128 + wr + mf * 16 + (lane >> 4) * 4 + r;
#pragma unroll
        for (int nf = 0; nf < 4; ++nf)
          qh[(size_t)row * 768 + colv[nf]] = f2bf((acc[mf][nf][r] + bzv[nf]) * zzv[nf]);
      }
  } else {
    const int bsel = mt >> 3;
    const int base_b = bsel << 10;
    const int nb = nbd[bsel];
#pragma unroll
    for (int mf = 0; mf < 2; ++mf)
#pragma unroll
      for (int r = 0; r < 4; ++r){
        int grow = mt * 128 + wr + mf * 16 + (lane >> 4) * 4 + r;
        int row_local = grow - base_b;
        if (row_local >= nb) continue;       // pad row (kc garbage OK; vtc stays 0)
        if (z == 1){
#pragma unroll
          for (int nf = 0; nf < 4; ++nf)
            kc[(size_t)grow * 768 + colv[nf]] =
                f2bf((acc[mf][nf][r] + bzv[nf]) * zzv[nf]);
        } else {
#pragma unroll
          for (int nf = 0; nf < 4; ++nf){
            int hh = colv[nf] >> 6, dd = colv[nf] & 63;
            vtc[((size_t)(bsel * 12 + hh) * 64 + dd) * 1024 + row_local] =
                f2bf((acc[mf][nf][r] + bzv[nf]) * zzv[nf]);
          }
        }
      }
  }
}

// ---------------------------------------------------------------------------
// Flash attention (r11-proven attn_fwd7): 4 waves, K/V double-buffered in
// LDS, swapped-QK^T in-register-P, T5 setprio.  kc base = b*1024.
// ---------------------------------------------------------------------------
__global__ __launch_bounds__(256) void attn_fwd7(
    const us* __restrict__ qh, const us* __restrict__ kc,
    const us* __restrict__ vtc, const int* __restrict__ nbd,
    us* __restrict__ ao)
{
  const int flat = blockIdx.x + 16 * blockIdx.y + 192 * blockIdx.z;
  const int xcd = flat & 7, c = flat >> 3;
  const int pair = xcd * 6 + (c >> 4);
  const int qt = c & 15, h = pair % 12, b = pair / 12;
  const int tid = threadIdx.x, lane = tid & 63, w = tid >> 6;

  const int nbv = nbd[b];
  const int base_b = b << 10;
  const int nt = (nbv + 63) >> 6;

  __shared__ __align__(16) us Ks[2][64 * 64];
  __shared__ __align__(16) us Vs[2][64 * 64];

  short8 qf[2];
#pragma unroll
  for (int ks = 0; ks < 2; ++ks)
    qf[ks] = *(const short8*)(qh +
              (size_t)(b * 1024 + qt * 64 + w * 16 + (lane & 15)) * 768 +
              h * 64 + ks * 32 + (lane >> 4) * 8);

  short8 kr[2], vr[2];
  auto KVLOAD = [&](int kt){
#pragma unroll
    for (int p = 0; p < 2; ++p){
      int cc = p * 256 + tid, row = cc >> 3, db = (cc & 7) * 8;
      kr[p] = *(const short8*)(kc + (size_t)(base_b + kt * 64 + row) * 768 + h * 64 + db);
      vr[p] = *(const short8*)(vtc + ((size_t)((b * 12 + h) * 64 + row)) * 1024 + kt * 64 + db);
    }
  };
  auto KVWRITE = [&](int buf){
#pragma unroll
    for (int p = 0; p < 2; ++p){
      int cc = p * 256 + tid, row = cc >> 3, db = (cc & 7) * 8;
      int byte = (row * 128 + db * 2) ^ ((row & 7) << 4);
      *(short8*)((char*)Ks[buf] + byte) = kr[p];
      *(short8*)((char*)Vs[buf] + byte) = vr[p];
    }
  };
  KVLOAD(0); KVWRITE(0);
  __syncthreads();

  const int bpbase = (((lane & 16) << 1) | (lane & 15)) << 2;
  const bool hi5 = (lane & 32) != 0;

  float lsum = 0.f;
  f32x4 o[4] = {};
  int cur = 0;
  for (int kt = 0; kt < nt; ++kt){
    if (kt + 1 < nt) KVLOAD(kt + 1);

    // S^T = K Q^T
    f32x4 s[4] = {};
    __builtin_amdgcn_s_setprio(1);
#pragma unroll
    for (int ks = 0; ks < 2; ++ks)
#pragma unroll
      for (int f = 0; f < 4; ++f){
        int row = f * 16 + (lane & 15);
        short8 kf = *(const short8*)((const char*)Ks[cur] +
                    ((row * 128 + ks * 64 + (lane >> 4) * 16) ^ ((row & 7) << 4)));
        s[f] = MFMA16(kf, qf[ks], s[f]);
      }
    __builtin_amdgcn_s_setprio(0);

    float p_[4][4];
#pragma unroll
    for (int f = 0; f < 4; ++f)
#pragma unroll
      for (int r = 0; r < 4; ++r)
        p_[f][r] = __expf(s[f][r] * 0.125f);
    if (kt == nt - 1){
      int kb = kt * 64 + ((lane >> 4) << 2);
#pragma unroll
      for (int f = 0; f < 4; ++f)
#pragma unroll
        for (int r = 0; r < 4; ++r)
          p_[f][r] = (kb + f * 16 + r < nbv) ? p_[f][r] : 0.f;
    }
#pragma unroll
    for (int f = 0; f < 4; ++f)
      lsum += (p_[f][0] + p_[f][1]) + (p_[f][2] + p_[f][3]);

    unsigned pk[4][2];
#pragma unroll
    for (int f = 0; f < 4; ++f){
      pk[f][0] = (unsigned)f2bf(p_[f][0]) | ((unsigned)f2bf(p_[f][1]) << 16);
      pk[f][1] = (unsigned)f2bf(p_[f][2]) | ((unsigned)f2bf(p_[f][3]) << 16);
    }

    PU pa0, pa1;
#pragma unroll
    for (int j = 0; j < 4; ++j){
      int addr = bpbase + ((j & 2) << 5);
      int wsel = j & 1;
      int t0 = __builtin_amdgcn_ds_bpermute(addr, (int)pk[0][wsel]);
      int t1 = __builtin_amdgcn_ds_bpermute(addr, (int)pk[1][wsel]);
      int t2 = __builtin_amdgcn_ds_bpermute(addr, (int)pk[2][wsel]);
      int t3 = __builtin_amdgcn_ds_bpermute(addr, (int)pk[3][wsel]);
      pa0.w[j] = hi5 ? t1 : t0;
      pa1.w[j] = hi5 ? t3 : t2;
    }

    __builtin_amdgcn_s_setprio(1);
#pragma unroll
    for (int df = 0; df < 4; ++df){
      int vrow = df * 16 + (lane & 15);
      short8 vb0 = *(const short8*)((const char*)Vs[cur] +
                   ((vrow * 128 + 0  + (lane >> 4) * 16) ^ ((vrow & 7) << 4)));
      short8 vb1 = *(const short8*)((const char*)Vs[cur] +
                   ((vrow * 128 + 64 + (lane >> 4) * 16) ^ ((vrow & 7) << 4)));
      o[df] = MFMA16(pa0.v, vb0, o[df]);
      o[df] = MFMA16(pa1.v, vb1, o[df]);
    }
    __builtin_amdgcn_s_setprio(0);

    if (kt + 1 < nt) KVWRITE(cur ^ 1);
    __syncthreads();
    cur ^= 1;
  }

  float l = lsum;
  l += __shfl_xor(l, 16, 64);
  l += __shfl_xor(l, 32, 64);
  float linv[4];
#pragma unroll
  for (int r = 0; r < 4; ++r)
    linv[r] = __builtin_amdgcn_rcpf(__shfl(l, (lane >> 4) * 4 + r, 64));

#pragma unroll
  for (int df = 0; df < 4; ++df)
#pragma unroll
    for (int r = 0; r < 4; ++r){
      int qrow = qt * 64 + w * 16 + (lane >> 4) * 4 + r;
      int dcol = df * 16 + (lane & 15);
      ao[(size_t)(b * 1024 + qrow) * 768 + h * 64 + dcol] = f2bf(o[df][r] * linv[r]);
    }
}

// ---------------------------------------------------------------------------
// Output projection: 512-thread / 8-wave template (r14-proven), fp32 scatter.
// ---------------------------------------------------------------------------
__global__ __launch_bounds__(512, 1) void out_gemm8(
    const us* __restrict__ ain, const us* __restrict__ wo,
    const float* __restrict__ bo, float* __restrict__ dout)
{
  __shared__ __align__(16) us As[2][128 * 64];
  __shared__ __align__(16) us Bs[2][128 * 64];

  const int tid = threadIdx.x, lane = tid & 63, w = tid >> 6;
  const int wr = (w >> 1) * 32, wc = (w & 1) * 64;
  const int flat = blockIdx.x + blockIdx.y * 32;
  const int xcd = flat & 7, c = flat >> 3;
  const int mt = xcd * 4 + (c & 3);
  const int nt = c >> 2;

  f32x4 acc[2][4] = {};

  auto STAGE = [&](int kt, int buf){
#pragma unroll
    for (int p = 0; p < 2; ++p){
      int chunk = p * 512 + tid;
      int row = chunk >> 3;
      int colb = ((chunk & 7) ^ (row & 7)) * 8;
      GL16(ain + (size_t)(mt * 128 + row) * 768 + kt * 64 + colb,
           As[buf] + (p * 512 + w * 64) * 8);
      GL16(wo  + (size_t)(nt * 128 + row) * 768 + kt * 64 + colb,
           Bs[buf] + (p * 512 + w * 64) * 8);
    }
  };

  STAGE(0, 0);
  STAGE(1, 1);
  for (int kt = 0; kt < 12; ++kt){
    const int cur = kt & 1;
    if (kt < 11) asm volatile("s_waitcnt vmcnt(4)" ::: "memory");
    else         asm volatile("s_waitcnt vmcnt(0)" ::: "memory");
    __builtin_amdgcn_s_barrier();

#pragma unroll
    for (int ks = 0; ks < 2; ++ks){
      short8 af[2], bf4[4];
#pragma unroll
      for (int mf = 0; mf < 2; ++mf){
        int row = wr + mf * 16 + (lane & 15);
        int byte = (row * 128 + ks * 64 + (lane >> 4) * 16) ^ ((row & 7) << 4);
        af[mf] = *(const short8*)((const char*)As[cur] + byte);
      }
#pragma unroll
      for (int nf = 0; nf < 4; ++nf){
        int row = wc + nf * 16 + (lane & 15);
        int byte = (row * 128 + ks * 64 + (lane >> 4) * 16) ^ ((row & 7) << 4);
        bf4[nf] = *(const short8*)((const char*)Bs[cur] + byte);
      }
#pragma unroll
      for (int mf = 0; mf < 2; ++mf)
#pragma unroll
        for (int nf = 0; nf < 4; ++nf)
          acc[mf][nf] = MFMA16(af[mf], bf4[nf], acc[mf][nf]);
    }

    asm volatile("s_waitcnt lgkmcnt(0)" ::: "memory");
    __builtin_amdgcn_s_barrier();
    if (kt < 10) STAGE(kt + 2, cur);
  }

#pragma unroll
  for (int nf = 0; nf < 4; ++nf){
    int col = nt * 128 + wc + nf * 16 + (lane & 15);
    float bz = bo[col];
#pragma unroll
    for (int mf = 0; mf < 2; ++mf)
#pragma unroll
      for (int r = 0; r < 4; ++r){
        int row = mt * 128 + wr + mf * 16 + (lane >> 4) * 4 + r;
        int n = row & 1023, bsel = row >> 10;
        dout[(size_t)(n * 4 + bsel) * 768 + col] = acc[mf][nf][r] + bz;
      }
  }
}

extern "C" void kernel_launch(void* const* d_in, const int* in_sizes, int n_in,
                              void* d_out, int out_size, void* d_ws, size_t ws_size,
                              hipStream_t stream)
{
  const float* q    = (const float*)d_in[0];
  const float* k    = (const float*)d_in[1];
  const float* v    = (const float*)d_in[2];
  const int*   mask = (const int*)d_in[3];
  const float* Wq   = (const float*)d_in[4];
  const float* bq   = (const float*)d_in[5];
  const float* Wk   = (const float*)d_in[6];
  const float* bk   = (const float*)d_in[7];
  const float* Wv   = (const float*)d_in[8];
  const float* bv   = (const float*)d_in[9];
  const float* Wo   = (const float*)d_in[10];
  const float* bo   = (const float*)d_in[11];
  const float* zeta = (const float*)d_in[12];

  // bf16 xq + per-batch-compacted xk parked inside d_out
  us* xbq = (us*)d_out;
  us* xbk = xbq + 3145728;
  // workspace layout
  us* xbv = (us*)d_ws;          // per-batch compacted rows [b*1024+rank][768]
  us* wb  = xbv + 3145728;      // 4 x 768 x 768 bf16 weights
  us* qh  = wb  + 2359296;
  us* kc  = qh  + 3145728;      // compacted K [b*1024+rank][768] (pad garbage OK)
  us* vtc = kc  + 3145728;      // compacted V^T [b][h][d][rank] (pad zeroed)
  int* nbd = (int*)(vtc + 3145728);
  us* ao = xbv;                 // reuse: xbv dead after qkv_gemm9

  prep<<<7300, 256, 0, stream>>>(q, k, v, Wq, Wk, Wv, Wo, mask,
                                 xbq, xbk, xbv, wb, (f32x4*)vtc, nbd);
  qkv_gemm9<<<dim3(32, 6, 3), 512, 0, stream>>>(xbq, xbk, xbv, wb, bq, bk, bv,
                                                zeta, nbd, qh, kc, vtc);
  attn_fwd7<<<dim3(16, 12, 4), 256, 0, stream>>>(qh, kc, vtc, nbd, ao);
  out_gemm8<<<dim3(32, 6, 1), 512, 0, stream>>>(ao, wb + 3 * 589824, bo, (float*)d_out);
}